// Round 1
// baseline (982.516 us; speedup 1.0000x reference)
//
#include <hip/hip_runtime.h>
#include <hip/hip_bf16.h>
#include <math.h>

// Problem constants
#define B_  8
#define C_  64
#define H_  256
#define W_  256
#define S_  3
#define J_  192          // S_*C_ intermediate channels
#define HW_ (H_*W_)
#define TH_ 32           // K2 tile height (full 256-col width tiles)

struct Taps {
    float g0[5];    // sigma 0.5, r=2
    float g1[7];    // sigma 1.0, r=3
    float g2[13];   // sigma 2.0, r=6
};

// ---------------------------------------------------------------------------
// K1: channel mix (1x1 conv) BEFORE blur (commutes with depthwise blur).
// v[bb, s*64+o, h, w] = sum_c fusion_w[o, s*64+c] * x[b, c, h, w]   (bf16 out)
// One block = one (b, h) row; thread = one column; x row held in registers.
// ---------------------------------------------------------------------------
__global__ __launch_bounds__(256) void k1_mix(
    const float* __restrict__ x, const float* __restrict__ fw,
    __hip_bfloat16* __restrict__ v, int b0)
{
    int bh  = blockIdx.x;
    int h   = bh & (H_ - 1);
    int b   = (bh >> 8) + b0;       // global batch
    int bb  = bh >> 8;              // local (chunk) batch
    int col = threadIdx.x;

    const float* xp = x + (size_t)b * C_ * HW_ + (size_t)h * W_ + col;
    float xr[C_];
#pragma unroll
    for (int c = 0; c < C_; ++c) xr[c] = xp[(size_t)c * HW_];

    size_t vbase = (size_t)bb * J_ * HW_ + (size_t)h * W_ + col;
    for (int j = 0; j < J_; ++j) {
        // j = s*64 + o  ->  W row = fusion_w[o, s*64 : s*64+64]
        const float* wr = fw + (size_t)(j & 63) * J_ + (size_t)(j >> 6) * C_;
        float a0 = 0.f, a1 = 0.f, a2 = 0.f, a3 = 0.f;
#pragma unroll
        for (int c = 0; c < C_; c += 4) {
            a0 += wr[c + 0] * xr[c + 0];
            a1 += wr[c + 1] * xr[c + 1];
            a2 += wr[c + 2] * xr[c + 2];
            a3 += wr[c + 3] * xr[c + 3];
        }
        v[vbase + (size_t)j * HW_] = __float2bfloat16((a0 + a1) + (a2 + a3));
    }
}

// ---------------------------------------------------------------------------
// K2: per (b, o, row-tile): separable blur of v[s*64+o] for the 3 scales,
// summed, + bias + residual x.  hblur reads v straight from global (L1/L2
// absorbs the 4-col window overlap), writes tmp rows to LDS; vblur does a
// register sliding window over LDS rows.  Each thread owns a 4-col x 8-row
// patch of the 256x32 tile.
// ---------------------------------------------------------------------------
template<int R>
__device__ __forceinline__ void blur_one(
    const __hip_bfloat16* __restrict__ vplane, const float* __restrict__ g,
    float* __restrict__ tmp, int h0, int cg, int rw, float4* acc)
{
    const int NR = TH_ + 2 * R;     // tmp rows
    const int K  = 2 * R + 1;       // taps
    const int c0 = cg * 4;

    // ---- horizontal blur: rows rw, rw+4, ... ----
    for (int row = rw; row < NR; row += 4) {
        int gh = h0 - R + row;
        float o0 = 0.f, o1 = 0.f, o2 = 0.f, o3 = 0.f;
        if (gh >= 0 && gh < H_) {
            const __hip_bfloat16* vr = vplane + (size_t)gh * W_;
            float win[2 * R + 4];
#pragma unroll
            for (int i = 0; i < 2 * R + 4; ++i) {
                int c = c0 - R + i;
                win[i] = (c >= 0 && c < W_) ? __bfloat162float(vr[c]) : 0.f;
            }
#pragma unroll
            for (int d = 0; d < K; ++d) {
                float gd = g[d];
                o0 += gd * win[d + 0];
                o1 += gd * win[d + 1];
                o2 += gd * win[d + 2];
                o3 += gd * win[d + 3];
            }
        }
        *(float4*)&tmp[row * W_ + c0] = make_float4(o0, o1, o2, o3);
    }
    __syncthreads();

    // ---- vertical blur: strip rows [rw*8, rw*8+8), register sliding window
    float4 win[K];
    const int base = rw * 8;
#pragma unroll
    for (int k = 0; k < 8 + 2 * R; ++k) {
        win[k % K] = *(const float4*)&tmp[(base + k) * W_ + c0];
        if (k >= 2 * R) {
            float4 a = acc[k - 2 * R];
#pragma unroll
            for (int d = 0; d < K; ++d) {
                float gd = g[d];
                const float4 wv = win[(k - 2 * R + d) % K];
                a.x += gd * wv.x; a.y += gd * wv.y;
                a.z += gd * wv.z; a.w += gd * wv.w;
            }
            acc[k - 2 * R] = a;
        }
    }
    __syncthreads();
}

__global__ __launch_bounds__(256) void k2_blur(
    const __hip_bfloat16* __restrict__ v, const float* __restrict__ x,
    const float* __restrict__ bias, float* __restrict__ out,
    Taps taps, int b0)
{
    __shared__ float tmp[(TH_ + 12) * W_];   // 44*256*4 = 45056 B

    int t    = blockIdx.x;
    int tile = t & 7;            // H_/TH_ = 8 tiles
    int o    = (t >> 3) & 63;
    int bb   = t >> 9;           // local batch
    int b    = bb + b0;
    int h0   = tile * TH_;
    int cg   = threadIdx.x & 63;
    int rw   = threadIdx.x >> 6;
    int c0   = cg * 4;

    float4 acc[TH_ / 4];         // 8 rows x 4 cols per thread
#pragma unroll
    for (int i = 0; i < TH_ / 4; ++i) acc[i] = make_float4(0, 0, 0, 0);

    const __hip_bfloat16* vp = v + (size_t)(bb * J_ + o) * HW_;
    blur_one<2>(vp,              taps.g0, tmp, h0, cg, rw, acc);
    blur_one<3>(vp + (size_t)C_ * HW_,     taps.g1, tmp, h0, cg, rw, acc);
    blur_one<6>(vp + (size_t)(2 * C_) * HW_, taps.g2, tmp, h0, cg, rw, acc);

    // epilogue: + x + bias
    const float* xp = x   + ((size_t)b * C_ + o) * HW_ + (size_t)h0 * W_;
    float*       op = out + ((size_t)b * C_ + o) * HW_ + (size_t)h0 * W_;
    float bo = bias[o];
#pragma unroll
    for (int i = 0; i < TH_ / 4; ++i) {
        int row = rw * 8 + i;
        float4 xv = *(const float4*)&xp[(size_t)row * W_ + c0];
        float4 r;
        r.x = xv.x + bo + acc[i].x;
        r.y = xv.y + bo + acc[i].y;
        r.z = xv.z + bo + acc[i].z;
        r.w = xv.w + bo + acc[i].w;
        *(float4*)&op[(size_t)row * W_ + c0] = r;
    }
}

// ---------------------------------------------------------------------------
static void make_taps(Taps& t)
{
    auto fill = [](float* g, int k, double sigma) {
        int r = k / 2;
        double s = 0.0;
        for (int i = 0; i < k; ++i) {
            double w = exp(-(double)((i - r) * (i - r)) / (2.0 * sigma * sigma));
            g[i] = (float)w;
            s += w;
        }
        for (int i = 0; i < k; ++i) g[i] = (float)((double)g[i] / s);
    };
    fill(t.g0, 5, 0.5);
    fill(t.g1, 7, 1.0);
    fill(t.g2, 13, 2.0);
}

extern "C" void kernel_launch(void* const* d_in, const int* in_sizes, int n_in,
                              void* d_out, int out_size, void* d_ws, size_t ws_size,
                              hipStream_t stream)
{
    const float* x  = (const float*)d_in[0];
    const float* fw = (const float*)d_in[1];
    const float* fb = (const float*)d_in[2];
    float* out = (float*)d_out;
    __hip_bfloat16* v = (__hip_bfloat16*)d_ws;

    Taps taps;
    make_taps(taps);

    const size_t per_batch = (size_t)J_ * HW_ * sizeof(__hip_bfloat16); // 25.2 MB
    int nb = (int)(ws_size / per_batch);
    if (nb > B_) nb = B_;
    if (nb < 1) return;  // workspace too small — fail visibly rather than corrupt

    for (int b0 = 0; b0 < B_; b0 += nb) {
        int n = (B_ - b0 < nb) ? (B_ - b0) : nb;
        k1_mix<<<dim3(n * H_), dim3(256), 0, stream>>>(x, fw, v, b0);
        k2_blur<<<dim3(n * C_ * (H_ / TH_)), dim3(256), 0, stream>>>(v, x, fb, out, taps, b0);
    }
}

// Round 2
// 494.753 us; speedup vs baseline: 1.9859x; 1.9859x over previous
//
#include <hip/hip_runtime.h>
#include <hip/hip_bf16.h>
#include <math.h>

// Problem constants
#define B_  8
#define C_  64
#define H_  256
#define W_  256
#define HW_ (H_*W_)
#define J_  192          // 3*C intermediate channels
#define TH_ 32           // K2 tile height

typedef __attribute__((ext_vector_type(8))) short short8;
typedef __attribute__((ext_vector_type(4))) float f32x4;

// ---- bf16 helpers (RNE) ----
__device__ __forceinline__ ushort f2bf(float f) {
    union { float f; uint u; } v; v.f = f;
    uint u = v.u;
    return (ushort)((u + 0x7fffu + ((u >> 16) & 1u)) >> 16);
}
__device__ __forceinline__ float bf2f(ushort s) {
    union { uint u; float f; } v; v.u = ((uint)s) << 16;
    return v.f;
}
__device__ __forceinline__ uint pk(float a, float b) {
    return (uint)f2bf(a) | ((uint)f2bf(b) << 16);
}

// ---------------------------------------------------------------------------
// K1: v[b, j, px] = sum_c Wm[j,c] * x[b,c,px]   (bf16 out), via MFMA.
//   Wm[j][c] = fw[(j&63)*192 + (j>>6)*64 + c]   (mix commutes with blur)
// Block = (b, 256-px strip). x-tile staged to LDS transposed [px][c] in bf16,
// 8B granules XOR-swizzled: slot(px, c4) = c4 ^ ((px>>2)&15) ^ ((px&3)<<2).
// MFMA 16x16x32: A = x (m=px, k=c from LDS), B = Wm (n=j, from global regs),
// D: col=lane&15 = j, row=(lane>>4)*4+reg = px -> 4 consecutive px packed 8B.
// ---------------------------------------------------------------------------
__global__ __launch_bounds__(256) void k1_mix(
    const float* __restrict__ x, const float* __restrict__ fw,
    ushort* __restrict__ v)
{
    __shared__ ushort lxs[256 * 64];   // 32 KB

    const int b      = blockIdx.x >> 8;
    const int pxbase = (blockIdx.x & 255) << 8;
    const int t      = threadIdx.x;
    const int lane   = t & 63;
    const int wv_    = t >> 6;

    // ---- stage x [64c x 256px] fp32 -> LDS bf16 transposed ----
    {
        const int cg = lane;            // px-quad group 0..63
        const float* xb = x + (size_t)b * C_ * HW_ + pxbase + 4 * cg;
#pragma unroll
        for (int i = 0; i < 4; ++i) {
            const int cb = wv_ * 4 + i * 16;    // c base (4 consecutive c)
            const int c4 = wv_ + i * 4;         // granule index
            float4 r0 = *(const float4*)(xb + (size_t)(cb + 0) * HW_);
            float4 r1 = *(const float4*)(xb + (size_t)(cb + 1) * HW_);
            float4 r2 = *(const float4*)(xb + (size_t)(cb + 2) * HW_);
            float4 r3 = *(const float4*)(xb + (size_t)(cb + 3) * HW_);
            const int sbase = c4 ^ (cg & 15);
            ushort* dst = &lxs[(4 * cg) * 64];
            *(uint2*)(dst + 0*64 + ((sbase ^ 0) * 4)) = make_uint2(pk(r0.x, r1.x), pk(r2.x, r3.x));
            *(uint2*)(dst + 1*64 + ((sbase ^ 4) * 4)) = make_uint2(pk(r0.y, r1.y), pk(r2.y, r3.y));
            *(uint2*)(dst + 2*64 + ((sbase ^ 8) * 4)) = make_uint2(pk(r0.z, r1.z), pk(r2.z, r3.z));
            *(uint2*)(dst + 3*64 + ((sbase ^ 12) * 4)) = make_uint2(pk(r0.w, r1.w), pk(r2.w, r3.w));
        }
    }

    // ---- W fragments (B operand), 3 j-tiles per wave, kept in regs ----
    const int n = lane & 15;           // j within tile / B-frag col
    const int q = lane >> 4;           // quad
    union Frag { short8 v; uint u[4]; };
    Frag wf[3][2];
#pragma unroll
    for (int i = 0; i < 3; ++i) {
        const int j  = (wv_ * 3 + i) * 16 + n;
        const float* wr = fw + (size_t)(j & 63) * J_ + (j >> 6) * 64;
#pragma unroll
        for (int kh = 0; kh < 2; ++kh) {
            float4 w0 = *(const float4*)(wr + kh * 32 + q * 8);
            float4 w1 = *(const float4*)(wr + kh * 32 + q * 8 + 4);
            wf[i][kh].u[0] = pk(w0.x, w0.y);
            wf[i][kh].u[1] = pk(w0.z, w0.w);
            wf[i][kh].u[2] = pk(w1.x, w1.y);
            wf[i][kh].u[3] = pk(w1.z, w1.w);
        }
    }

    __syncthreads();

    // ---- 16 px-tiles x 3 j-tiles ----
    for (int mt = 0; mt < 16; ++mt) {
        const int px = mt * 16 + (lane & 15);          // A-frag m
        const ushort* row = &lxs[px * 64];
        const int s = ((px >> 2) & 15) ^ ((px & 3) << 2);
        Frag a0, a1;
        {
            uint2 lo  = *(const uint2*)&row[((2*q    ) ^ s) * 4];
            uint2 hi  = *(const uint2*)&row[((2*q + 1) ^ s) * 4];
            a0.u[0] = lo.x;  a0.u[1] = lo.y;  a0.u[2] = hi.x;  a0.u[3] = hi.y;
            uint2 lo1 = *(const uint2*)&row[((8 + 2*q    ) ^ s) * 4];
            uint2 hi1 = *(const uint2*)&row[((8 + 2*q + 1) ^ s) * 4];
            a1.u[0] = lo1.x; a1.u[1] = lo1.y; a1.u[2] = hi1.x; a1.u[3] = hi1.y;
        }
#pragma unroll
        for (int i = 0; i < 3; ++i) {
            f32x4 acc = {0.f, 0.f, 0.f, 0.f};
            acc = __builtin_amdgcn_mfma_f32_16x16x32_bf16(a0.v, wf[i][0].v, acc, 0, 0, 0);
            acc = __builtin_amdgcn_mfma_f32_16x16x32_bf16(a1.v, wf[i][1].v, acc, 0, 0, 0);
            const int j   = (wv_ * 3 + i) * 16 + n;
            const int pxg = pxbase + mt * 16 + q * 4;  // D row = q*4 + reg
            *(uint2*)&v[(size_t)(b * J_ + j) * HW_ + pxg] =
                make_uint2(pk(acc[0], acc[1]), pk(acc[2], acc[3]));
        }
    }
}

// ---------------------------------------------------------------------------
// K2: out[b,o] = x[b,o] + bias[o] + sum_s vblur_s(hblur_s(v[b, s*64+o]))
// Block = (b, o, 32-row tile); thread owns 4 cols x 8 rows.
// hblur: aligned 8B granule loads from global (L1 absorbs window overlap),
// writes bf16 tmp rows to LDS. vblur: streams tmp rows, scatter-accumulate.
// ---------------------------------------------------------------------------
struct Taps {
    float g0[5];    // sigma 0.5, r=2
    float g1[7];    // sigma 1.0, r=3
    float g2[13];   // sigma 2.0, r=6
};

template<int R, int G>
__device__ __forceinline__ void blur_one(
    const ushort* __restrict__ vplane, const float* __restrict__ g,
    ushort* __restrict__ tmp, int h0, int cg, int rw, float4* acc)
{
    const int NR  = TH_ + 2 * R;     // tmp rows
    const int K   = 2 * R + 1;       // taps
    const int NG  = 2 * G + 1;       // granules loaded per row
    const int OFF = 4 * G - R;       // window offset (>=0 for all scales)
    const int c0  = cg * 4;

    // ---- horizontal blur ----
    for (int row = rw; row < NR; row += 4) {
        const int gh = h0 - R + row;
        float o0 = 0.f, o1 = 0.f, o2 = 0.f, o3 = 0.f;
        if (gh >= 0 && gh < H_) {
            const ushort* vr = vplane + (size_t)gh * W_;
            float win[NG * 4];
#pragma unroll
            for (int gi = 0; gi < NG; ++gi) {
                const int gg = cg - G + gi;
                uint2 d = (gg >= 0 && gg < 64) ? *(const uint2*)(vr + gg * 4)
                                               : make_uint2(0u, 0u);
                win[gi*4+0] = bf2f((ushort)(d.x & 0xffffu));
                win[gi*4+1] = bf2f((ushort)(d.x >> 16));
                win[gi*4+2] = bf2f((ushort)(d.y & 0xffffu));
                win[gi*4+3] = bf2f((ushort)(d.y >> 16));
            }
#pragma unroll
            for (int dd = 0; dd < K; ++dd) {
                const float gd = g[dd];
                o0 += gd * win[OFF + dd + 0];
                o1 += gd * win[OFF + dd + 1];
                o2 += gd * win[OFF + dd + 2];
                o3 += gd * win[OFF + dd + 3];
            }
        }
        *(uint2*)&tmp[row * W_ + c0] = make_uint2(pk(o0, o1), pk(o2, o3));
    }
    __syncthreads();

    // ---- vertical blur: stream tmp rows, scatter into acc ----
    const int base = rw * 8;
#pragma unroll
    for (int k = 0; k < 8 + 2 * R; ++k) {
        uint2 raw = *(const uint2*)&tmp[(base + k) * W_ + c0];
        const float f0 = bf2f((ushort)(raw.x & 0xffffu));
        const float f1 = bf2f((ushort)(raw.x >> 16));
        const float f2 = bf2f((ushort)(raw.y & 0xffffu));
        const float f3 = bf2f((ushort)(raw.y >> 16));
        const int ilo = (k - 2 * R) > 0 ? (k - 2 * R) : 0;
        const int ihi = k < 7 ? k : 7;
#pragma unroll
        for (int i = ilo; i <= ihi; ++i) {
            const float gd = g[k - i];
            acc[i].x += gd * f0;
            acc[i].y += gd * f1;
            acc[i].z += gd * f2;
            acc[i].w += gd * f3;
        }
    }
    __syncthreads();
}

__global__ __launch_bounds__(256) void k2_blur(
    const ushort* __restrict__ v, const float* __restrict__ x,
    const float* __restrict__ bias, float* __restrict__ out,
    Taps taps)
{
    __shared__ ushort tmp[(TH_ + 12) * W_];   // 44*256*2 = 22528 B

    const int t    = blockIdx.x;
    const int tile = t & 7;
    const int o    = (t >> 3) & 63;
    const int b    = t >> 9;
    const int h0   = tile * TH_;
    const int cg   = threadIdx.x & 63;
    const int rw   = threadIdx.x >> 6;
    const int c0   = cg * 4;

    float4 acc[TH_ / 4];
#pragma unroll
    for (int i = 0; i < TH_ / 4; ++i) acc[i] = make_float4(0.f, 0.f, 0.f, 0.f);

    const ushort* vp = v + (size_t)(b * J_ + o) * HW_;
    blur_one<2, 1>(vp,                       taps.g0, tmp, h0, cg, rw, acc);
    blur_one<3, 1>(vp + (size_t)C_ * HW_,    taps.g1, tmp, h0, cg, rw, acc);
    blur_one<6, 2>(vp + (size_t)(2*C_) * HW_, taps.g2, tmp, h0, cg, rw, acc);

    // epilogue: + x + bias
    const float* xp = x   + ((size_t)b * C_ + o) * HW_ + (size_t)h0 * W_;
    float*       op = out + ((size_t)b * C_ + o) * HW_ + (size_t)h0 * W_;
    const float bo = bias[o];
#pragma unroll
    for (int i = 0; i < TH_ / 4; ++i) {
        const int row = rw * 8 + i;
        float4 xv = *(const float4*)&xp[(size_t)row * W_ + c0];
        float4 r;
        r.x = xv.x + bo + acc[i].x;
        r.y = xv.y + bo + acc[i].y;
        r.z = xv.z + bo + acc[i].z;
        r.w = xv.w + bo + acc[i].w;
        *(float4*)&op[(size_t)row * W_ + c0] = r;
    }
}

// ---------------------------------------------------------------------------
static void make_taps(Taps& t)
{
    auto fill = [](float* g, int k, double sigma) {
        int r = k / 2;
        double s = 0.0;
        for (int i = 0; i < k; ++i) {
            double w = exp(-(double)((i - r) * (i - r)) / (2.0 * sigma * sigma));
            g[i] = (float)w;
            s += w;
        }
        for (int i = 0; i < k; ++i) g[i] = (float)((double)g[i] / s);
    };
    fill(t.g0, 5, 0.5);
    fill(t.g1, 7, 1.0);
    fill(t.g2, 13, 2.0);
}

extern "C" void kernel_launch(void* const* d_in, const int* in_sizes, int n_in,
                              void* d_out, int out_size, void* d_ws, size_t ws_size,
                              hipStream_t stream)
{
    const float* x  = (const float*)d_in[0];
    const float* fw = (const float*)d_in[1];
    const float* fb = (const float*)d_in[2];
    float* out = (float*)d_out;
    ushort* v = (ushort*)d_ws;   // bf16 intermediate, 8*192*65536*2 = 201 MB
                                 // (round 1 proved ws_size covers it: one k1
                                 //  dispatch wrote the full 196608 KB)
    Taps taps;
    make_taps(taps);

    k1_mix<<<dim3(B_ * (HW_ / 256)), dim3(256), 0, stream>>>(x, fw, v);
    k2_blur<<<dim3(B_ * C_ * (H_ / TH_)), dim3(256), 0, stream>>>(v, x, fb, out, taps);
}